// Round 1
// 679.618 us; speedup vs baseline: 1.0267x; 1.0267x over previous
//
#include <hip/hip_runtime.h>

// out[n,o,hw] = r*C[n,o,hw] + g*C[n,31+o,hw] + b*C[n,62+o,hw] + C[n,93+o,hw]
// N=4, H=W=512, C_IN=4, C_OUT=31. Pure streaming: ~663 MB -> ~105 us floor @6.3 TB/s.
// This version: nontemporal coeff loads / out stores (no reuse -> skip cache
// allocate), and o-range split across grid.y=2 for 32 waves/CU occupancy.

#define C_OUT 31

typedef float f4 __attribute__((ext_vector_type(4)));

__global__ __launch_bounds__(256)
void ApplyCoeffs_23261542875222_kernel(const f4* __restrict__ coeff,
                                       const f4* __restrict__ inp,
                                       f4* __restrict__ out,
                                       int p4)  // HW/4 = float4-pixels per image
{
    int t = blockIdx.x * blockDim.x + threadIdx.x;
    int n = t / p4;            // image index
    int p = t - n * p4;        // float4-pixel index within image
    int h = blockIdx.y;        // o-half: 0 -> o in [0,16), 1 -> o in [16,31)

    // Input [N,3,HW]: r,g,b held in registers across the whole o-range.
    // Normal (cached) loads: 12.6 MB total, re-read by the second half -> L2/L3 hit.
    const f4* in_n = inp + (size_t)n * 3 * p4;
    f4 r = in_n[p];
    f4 g = in_n[p + p4];
    f4 b = in_n[p + 2 * p4];

    const int o0   = h ? 16 : 0;
    const int ocnt = h ? 15 : 16;

    // Coeff [N, 4*C_OUT, HW]; channel c = i*C_OUT + o.
    const size_t s = (size_t)C_OUT * p4;                     // i-group stride (in f4)
    const f4* co = coeff + (size_t)n * 4 * s + (size_t)o0 * p4 + p;
    f4*       on = out   + (size_t)n * s     + (size_t)o0 * p4 + p;

    #pragma unroll 4
    for (int o = 0; o < ocnt; ++o) {
        f4 c0 = __builtin_nontemporal_load(co);              // i=0 (r)
        f4 c1 = __builtin_nontemporal_load(co + s);          // i=1 (g)
        f4 c2 = __builtin_nontemporal_load(co + 2 * s);      // i=2 (b)
        f4 c3 = __builtin_nontemporal_load(co + 3 * s);      // i=3 (ones)
        f4 v;
        v[0] = fmaf(r[0], c0[0], fmaf(g[0], c1[0], fmaf(b[0], c2[0], c3[0])));
        v[1] = fmaf(r[1], c0[1], fmaf(g[1], c1[1], fmaf(b[1], c2[1], c3[1])));
        v[2] = fmaf(r[2], c0[2], fmaf(g[2], c1[2], fmaf(b[2], c2[2], c3[2])));
        v[3] = fmaf(r[3], c0[3], fmaf(g[3], c1[3], fmaf(b[3], c2[3], c3[3])));
        __builtin_nontemporal_store(v, on);
        co += p4;
        on += p4;
    }
}

extern "C" void kernel_launch(void* const* d_in, const int* in_sizes, int n_in,
                              void* d_out, int out_size, void* d_ws, size_t ws_size,
                              hipStream_t stream) {
    const float* coeff = (const float*)d_in[0];          // [4, 124, 512, 512]
    const float* inp   = (const float*)d_in[1];          // [4, 3, 512, 512]
    float* out         = (float*)d_out;                  // [4, 31, 512, 512]

    const int N = 4;
    const int HW = 512 * 512;
    const int P4 = HW / 4;              // 65536 float4-pixels per image
    const int total = N * P4;           // 262144 pixel-quad threads
    dim3 block(256);
    dim3 grid(total / 256, 2);          // 1024 x 2 blocks (o-range split)

    ApplyCoeffs_23261542875222_kernel<<<grid, block, 0, stream>>>(
        (const f4*)coeff, (const f4*)inp, (f4*)out, P4);
}